// Round 1
// baseline (254.979 us; speedup 1.0000x reference)
//
#include <hip/hip_runtime.h>

// Problem constants: B=2, S=2048, D=1024, H=16, HD=64
#define S_LEN 2048
#define NH 16
#define HD 64
#define DMODEL 1024

typedef __bf16 bf16x8 __attribute__((ext_vector_type(8)));
typedef float floatx4 __attribute__((ext_vector_type(4)));
typedef short short8 __attribute__((ext_vector_type(8)));

__device__ inline unsigned short f2bf(float f) {
    union { float f; unsigned u; } v; v.f = f;
    unsigned u = v.u;
    unsigned r = (u + 0x7FFFu + ((u >> 16) & 1u)) >> 16;  // RNE
    return (unsigned short)r;
}

__device__ __forceinline__ void gload_lds16(const void* g, void* l) {
    __builtin_amdgcn_global_load_lds(
        (const __attribute__((address_space(1))) unsigned int*)g,
        (__attribute__((address_space(3))) unsigned int*)l, 16, 0, 0);
}

// ---------------------------------------------------------------------------
// K0: prepass. fp32 -> bf16 for x, w_qkv, w_proj (RNE), and cos/sin table
// for RoPE (kills on-device libm trig in the GEMM epilogue).
// Pure streaming, ~50 MB total -> ~10 us.
// ---------------------------------------------------------------------------
__device__ __forceinline__ void cvt4(const float4* __restrict__ src,
                                     uint2* __restrict__ dst, int i) {
    float4 v = src[i];
    union { unsigned short u[4]; uint2 d; } o;
    o.u[0] = f2bf(v.x); o.u[1] = f2bf(v.y); o.u[2] = f2bf(v.z); o.u[3] = f2bf(v.w);
    dst[i] = o.d;
}

__global__ __launch_bounds__(256) void prep_kernel(
    const float* __restrict__ x, const float* __restrict__ wq,
    const float* __restrict__ wp, const float* __restrict__ freqs,
    unsigned short* __restrict__ xb, unsigned short* __restrict__ wqb,
    unsigned short* __restrict__ wpb, float2* __restrict__ cs)
{
    const int tid = blockIdx.x * 256 + threadIdx.x;
    const int nth = gridDim.x * 256;
    for (int i = tid; i < (4096 * 1024) / 4; i += nth) cvt4((const float4*)x, (uint2*)xb, i);
    for (int i = tid; i < (3072 * 1024) / 4; i += nth) cvt4((const float4*)wq, (uint2*)wqb, i);
    for (int i = tid; i < (1024 * 1024) / 4; i += nth) cvt4((const float4*)wp, (uint2*)wpb, i);
    for (int i = tid; i < S_LEN * 32; i += nth) {
        const float f = freqs[i];
        float2 c; c.x = cosf(f); c.y = sinf(f);
        cs[i] = c;
    }
}

// ---------------------------------------------------------------------------
// K1: qkv = x_bf16 @ w_qkv_bf16^T + b_qkv, fused RoPE (table) + scatter.
// m97 structure: 128x128 tile, BK=32, 4 waves (2x2, 64x64 each),
// global_load_lds width=16 staging (linear LDS), 16 MFMA / K-step / wave.
//  q -> [bh][s][hd] row-major, PRE-SCALED by 1/sqrt(HD)=0.125 (exact)
//  k -> blocked [bh][hdblk(8)][s(2048)][8]   (RoPE applied)
//  v -> blocked [bh][sblk(256)][hd(64)][8]   (transposed via LDS tile)
// ---------------------------------------------------------------------------
__global__ __launch_bounds__(256) void qkv_gemm_kernel(
    const unsigned short* __restrict__ xb, const unsigned short* __restrict__ wqb,
    const float* __restrict__ bias, const float2* __restrict__ cs,
    unsigned short* __restrict__ qb, unsigned short* __restrict__ kb,
    unsigned short* __restrict__ vb)
{
    // main loop: As(4096)+Bs(4096) shorts; V epilogue reuses as 128x72 tile
    __shared__ __align__(16) unsigned short smem[9216];
    unsigned short* As = smem;
    unsigned short* Bs = smem + 4096;

    const int t = threadIdx.x;
    const int mbase = (blockIdx.x / 24) * 128;   // 32 m-tiles
    const int nbase = (blockIdx.x % 24) * 128;   // 24 n-tiles
    const int wv = t >> 6, lane = t & 63;
    const int quad = lane >> 4, l16 = lane & 15;
    const int wr = wv >> 1, wc = wv & 1;

    floatx4 acc[4][4];
    #pragma unroll
    for (int m = 0; m < 4; m++)
        #pragma unroll
        for (int n = 0; n < 4; n++)
            #pragma unroll
            for (int r = 0; r < 4; r++) acc[m][n][r] = 0.f;

    // staging: thread t owns 16B chunk t (rows t>>2, col-chunk t&3), linear LDS
    const unsigned short* ag = xb + (size_t)(mbase + (t >> 2)) * DMODEL + (t & 3) * 8;
    const unsigned short* bg = wqb + (size_t)(nbase + (t >> 2)) * DMODEL + (t & 3) * 8;
    unsigned short* AsW0 = As + wv * 512;          // wave-uniform LDS bases
    unsigned short* AsW1 = As + 2048 + wv * 512;
    unsigned short* BsW0 = Bs + wv * 512;
    unsigned short* BsW1 = Bs + 2048 + wv * 512;

    int aoff[4], boff[4];
    #pragma unroll
    for (int m = 0; m < 4; m++) aoff[m] = (wr * 64 + m * 16 + l16) * 32 + quad * 8;
    #pragma unroll
    for (int n = 0; n < 4; n++) boff[n] = (wc * 64 + n * 16 + l16) * 32 + quad * 8;

    for (int k0 = 0; k0 < DMODEL; k0 += 32) {
        __syncthreads();                            // prev iter frag reads done
        gload_lds16(ag + k0, AsW0);
        gload_lds16(ag + 64 * DMODEL + k0, AsW1);
        gload_lds16(bg + k0, BsW0);
        gload_lds16(bg + 64 * DMODEL + k0, BsW1);
        __syncthreads();                            // drains vmcnt -> staged data visible
        bf16x8 af[4];
        #pragma unroll
        for (int m = 0; m < 4; m++) af[m] = *(const bf16x8*)&As[aoff[m]];
        #pragma unroll
        for (int n = 0; n < 4; n++) {
            bf16x8 bf = *(const bf16x8*)&Bs[boff[n]];
            #pragma unroll
            for (int m = 0; m < 4; m++)
                acc[m][n] = __builtin_amdgcn_mfma_f32_16x16x32_bf16(af[m], bf, acc[m][n], 0, 0, 0);
        }
    }

    // n-tile is 128 cols: never crosses a q/k/v part boundary (1024 % 128 == 0),
    // spans exactly 2 heads.
    const int part = nbase >> 10;                 // 0=q 1=k 2=v (uniform per block)
    const int bidx = mbase >> 11;
    const int s0   = mbase & 2047;

    if (part == 2) {
        // ---- V: bias, transpose 128(s) x 128(hd) tile via LDS in two s-halves
        unsigned short* Vt = smem;                // 128 hd x 72 s-pad = 9216 shorts
        const int hb = (nbase & 1023) >> 6;       // base head (0,2,4,..)
        float bvv[4];
        #pragma unroll
        for (int nt = 0; nt < 4; nt++) bvv[nt] = bias[nbase + wc * 64 + nt * 16 + l16];
        #pragma unroll
        for (int shalf = 0; shalf < 2; shalf++) {
            __syncthreads();                      // LDS free (main loop / prev pass done)
            if (wr == shalf) {
                #pragma unroll
                for (int nt = 0; nt < 4; nt++) {
                    const int hdl = wc * 64 + nt * 16 + l16;
                    #pragma unroll
                    for (int m = 0; m < 4; m++)
                        #pragma unroll
                        for (int r = 0; r < 4; r++)
                            Vt[hdl * 72 + m * 16 + quad * 4 + r] = f2bf(acc[m][nt][r] + bvv[nt]);
                }
            }
            __syncthreads();
            const int hdl = t & 127, sp = t >> 7;
            const size_t bh2 = (size_t)bidx * NH + hb + (hdl >> 6);
            #pragma unroll
            for (int c = 0; c < 4; c++) {
                const int sl0 = (sp * 4 + c) * 8;
                const int sg = s0 + shalf * 64 + sl0;
                short8 vv = *(const short8*)&Vt[hdl * 72 + sl0];
                *(short8*)&vb[((bh2 * 256 + (sg >> 3)) * 64 + (hdl & 63)) * 8] = vv;
            }
        }
    } else {
        // ---- Q/K: bias + RoPE from table. Pair = adjacent col = adjacent l16.
        const size_t bhb = (size_t)bidx * NH;
        const int odd = l16 & 1;
        #pragma unroll
        for (int nt = 0; nt < 4; nt++) {
            const int n_ = nbase + wc * 64 + nt * 16 + l16;
            const int hd = n_ & 63;
            const size_t bh = bhb + ((n_ & 1023) >> 6);
            const float bvv = bias[n_];
            const int ci = (nt * 16 + l16) >> 1;  // == hd>>1 (wc*64 ≡ 0 mod 64)
            #pragma unroll
            for (int m = 0; m < 4; m++) {
                #pragma unroll
                for (int r = 0; r < 4; r++) {
                    const int s = s0 + wr * 64 + m * 16 + quad * 4 + r;
                    float val = acc[m][nt][r] + bvv;
                    float other = __shfl_xor(val, 1, 64);
                    const float2 csv = cs[(size_t)s * 32 + ci];
                    float outv = odd ? fmaf(other, csv.y, val * csv.x)
                                     : fmaf(-other, csv.y, val * csv.x);
                    if (part == 0) {
                        qb[(bh * S_LEN + s) * HD + hd] = f2bf(outv * 0.125f);
                    } else {
                        kb[((bh * 8 + (hd >> 3)) * (size_t)S_LEN + s) * 8 + (hd & 7)] = f2bf(outv);
                    }
                }
            }
        }
    }
}

// ---------------------------------------------------------------------------
// K2: causal flash attention (R4/R6 winner, unchanged). No-max softmax;
// transposed QK; barrier-free P roundtrip; 1 barrier per tile; grid 1024.
// ---------------------------------------------------------------------------
__global__ __launch_bounds__(256, 4) void attn_kernel(
    const unsigned short* __restrict__ qb, const unsigned short* __restrict__ kb,
    const unsigned short* __restrict__ vbk, unsigned short* __restrict__ ao)
{
    __shared__ __align__(16) unsigned short Ks[8 * 512];
    __shared__ __align__(16) unsigned short Vt[8 * 512];
    __shared__ __align__(16) unsigned short Pw[4][16 * 72];

    const int t = threadIdx.x;
    const int wv = t >> 6, lane = t & 63, quad = lane >> 4, l16 = lane & 15;
    const int qt   = blockIdx.x >> 5;
    const int bhid = blockIdx.x & 31;
    const int h = bhid & 15, b = bhid >> 4;
    const size_t bh = (size_t)b * NH + h;
    const unsigned short* qg  = qb + bh * S_LEN * HD;
    const unsigned short* kgB = kb + bh * 8 * S_LEN * 8;
    const unsigned short* vgB = vbk + bh * 256 * 64 * 8;

    bf16x8 qf[2];
    {
        const unsigned short* q0 = qg + (size_t)(qt * 64 + wv * 16 + l16) * HD;
        qf[0] = *(const bf16x8*)&q0[quad * 8];
        qf[1] = *(const bf16x8*)&q0[32 + quad * 8];
    }

    bf16x8 ones;
    {
        union { short8 s; bf16x8 v; } o;
        for (int j = 0; j < 8; j++) o.s[j] = 0x3F80;
        ones = o.v;
    }

    floatx4 lfr = {0.f, 0.f, 0.f, 0.f};
    floatx4 Ofr[4];
    for (int nt = 0; nt < 4; nt++)
        for (int r = 0; r < 4; r++) Ofr[nt][r] = 0.f;

    const int ntiles = qt + 1;

    for (int kt = 0; kt < ntiles; kt++) {
        const int kbase = kt * 64;
        {
            const unsigned short* g0 = kgB + ((size_t)(2 * wv) * S_LEN + kbase + lane) * 8;
            gload_lds16(g0,             &Ks[(2 * wv) * 512]);
            gload_lds16(g0 + S_LEN * 8, &Ks[(2 * wv + 1) * 512]);
            const unsigned short* g1 = vgB + ((size_t)((kbase >> 3) + 2 * wv) * 64 + lane) * 8;
            gload_lds16(g1,          &Vt[(2 * wv) * 512]);
            gload_lds16(g1 + 64 * 8, &Vt[(2 * wv + 1) * 512]);
        }
        __syncthreads();

        float pex[4][4];
        #pragma unroll
        for (int sub = 0; sub < 4; sub++) {
            bf16x8 kf0 = *(const bf16x8*)&Ks[(0 * 4 + quad) * 512 + (sub * 16 + l16) * 8];
            bf16x8 kf1 = *(const bf16x8*)&Ks[(1 * 4 + quad) * 512 + (sub * 16 + l16) * 8];
            floatx4 sacc = {0.f, 0.f, 0.f, 0.f};
            sacc = __builtin_amdgcn_mfma_f32_16x16x32_bf16(kf0, qf[0], sacc, 0, 0, 0);
            sacc = __builtin_amdgcn_mfma_f32_16x16x32_bf16(kf1, qf[1], sacc, 0, 0, 0);
            #pragma unroll
            for (int r = 0; r < 4; r++) pex[sub][r] = sacc[r];
        }
        if (kt == qt) {
            const int q = qt * 64 + wv * 16 + l16;
            #pragma unroll
            for (int sub = 0; sub < 4; sub++)
                #pragma unroll
                for (int r = 0; r < 4; r++) {
                    const int key = kbase + sub * 16 + quad * 4 + r;
                    if (key > q) pex[sub][r] = -1e30f;
                }
        }
        #pragma unroll
        for (int sub = 0; sub < 4; sub++) {
            union { unsigned short s[4]; uint2 u; } pk;
            #pragma unroll
            for (int r = 0; r < 4; r++) pk.s[r] = f2bf(__expf(pex[sub][r]));
            *(uint2*)&Pw[wv][l16 * 72 + sub * 16 + quad * 4] = pk.u;
        }
        bf16x8 pf0 = *(const bf16x8*)&Pw[wv][l16 * 72 + quad * 8];
        bf16x8 pf1 = *(const bf16x8*)&Pw[wv][l16 * 72 + 32 + quad * 8];
        lfr = __builtin_amdgcn_mfma_f32_16x16x32_bf16(ones, pf0, lfr, 0, 0, 0);
        lfr = __builtin_amdgcn_mfma_f32_16x16x32_bf16(ones, pf1, lfr, 0, 0, 0);
        #pragma unroll
        for (int nt = 0; nt < 4; nt++) {
            bf16x8 v0 = *(const bf16x8*)&Vt[(0 * 4 + quad) * 512 + (nt * 16 + l16) * 8];
            bf16x8 v1 = *(const bf16x8*)&Vt[(1 * 4 + quad) * 512 + (nt * 16 + l16) * 8];
            Ofr[nt] = __builtin_amdgcn_mfma_f32_16x16x32_bf16(pf0, v0, Ofr[nt], 0, 0, 0);
            Ofr[nt] = __builtin_amdgcn_mfma_f32_16x16x32_bf16(pf1, v1, Ofr[nt], 0, 0, 0);
        }
        __syncthreads();
    }

    float linv[4];
    #pragma unroll
    for (int r = 0; r < 4; r++) {
        float lq = __shfl(lfr[0], (lane & 48) | (quad * 4 + r), 64);
        linv[r] = 1.f / lq;
    }
    #pragma unroll
    for (int nt = 0; nt < 4; nt++)
        #pragma unroll
        for (int r = 0; r < 4; r++) {
            const int s = qt * 64 + wv * 16 + quad * 4 + r;
            ao[((size_t)b * S_LEN + s) * DMODEL + h * HD + nt * 16 + l16] =
                f2bf(Ofr[nt][r] * linv[r]);
        }
}

// ---------------------------------------------------------------------------
// K3: out = ao @ w_proj_bf16^T + b_proj.  M=4096, N=1024, K=1024. fp32 out.
// m97 structure: 128x64 tile, BK=32, global_load_lds staging, grid 512 (2/CU).
// ---------------------------------------------------------------------------
__global__ __launch_bounds__(256) void proj_kernel(
    const unsigned short* __restrict__ a, const unsigned short* __restrict__ wpb,
    const float* __restrict__ bias, float* __restrict__ out)
{
    __shared__ __align__(16) unsigned short As[4096];
    __shared__ __align__(16) unsigned short Bs[2048];
    const int t = threadIdx.x;
    const int mbase = (blockIdx.x >> 4) * 128;   // 32 m-tiles
    const int nbase = (blockIdx.x & 15) * 64;    // 16 n-tiles
    const int wv = t >> 6, lane = t & 63, quad = lane >> 4, l16 = lane & 15;
    const int wr = wv >> 1, wc = wv & 1;

    floatx4 acc[4][2];
    #pragma unroll
    for (int m = 0; m < 4; m++)
        #pragma unroll
        for (int n = 0; n < 2; n++)
            #pragma unroll
            for (int r = 0; r < 4; r++) acc[m][n][r] = 0.f;

    const unsigned short* ag = a + (size_t)(mbase + (t >> 2)) * DMODEL + (t & 3) * 8;
    const unsigned short* bg = wpb + (size_t)(nbase + (t >> 2)) * DMODEL + (t & 3) * 8;
    unsigned short* AsW0 = As + wv * 512;
    unsigned short* AsW1 = As + 2048 + wv * 512;
    unsigned short* BsW0 = Bs + wv * 512;

    int aoff[4], boff[2];
    #pragma unroll
    for (int m = 0; m < 4; m++) aoff[m] = (wr * 64 + m * 16 + l16) * 32 + quad * 8;
    #pragma unroll
    for (int n = 0; n < 2; n++) boff[n] = (wc * 32 + n * 16 + l16) * 32 + quad * 8;

    for (int k0 = 0; k0 < DMODEL; k0 += 32) {
        __syncthreads();
        gload_lds16(ag + k0, AsW0);
        gload_lds16(ag + 64 * DMODEL + k0, AsW1);
        gload_lds16(bg + k0, BsW0);
        __syncthreads();
        bf16x8 af[4];
        #pragma unroll
        for (int m = 0; m < 4; m++) af[m] = *(const bf16x8*)&As[aoff[m]];
        #pragma unroll
        for (int n = 0; n < 2; n++) {
            bf16x8 bf = *(const bf16x8*)&Bs[boff[n]];
            #pragma unroll
            for (int m = 0; m < 4; m++)
                acc[m][n] = __builtin_amdgcn_mfma_f32_16x16x32_bf16(af[m], bf, acc[m][n], 0, 0, 0);
        }
    }

    #pragma unroll
    for (int n = 0; n < 2; n++) {
        const int nn = nbase + wc * 32 + n * 16 + l16;
        const float bvv = bias[nn];
        #pragma unroll
        for (int m = 0; m < 4; m++)
            #pragma unroll
            for (int r = 0; r < 4; r++)
                out[(size_t)(mbase + wr * 64 + m * 16 + quad * 4 + r) * DMODEL + nn] =
                    acc[m][n][r] + bvv;
    }
}

extern "C" void kernel_launch(void* const* d_in, const int* in_sizes, int n_in,
                              void* d_out, int out_size, void* d_ws, size_t ws_size,
                              hipStream_t stream) {
    const float* x      = (const float*)d_in[0];
    const float* freqs  = (const float*)d_in[2];
    const float* w_qkv  = (const float*)d_in[3];
    const float* b_qkv  = (const float*)d_in[4];
    const float* w_proj = (const float*)d_in[5];
    const float* b_proj = (const float*)d_in[6];
    float* out = (float*)d_out;

    unsigned short* ws = (unsigned short*)d_ws;
    const size_t HSZ = (size_t)2 * NH * S_LEN * HD;   // 4,194,304 shorts
    unsigned short* qb  = ws;
    unsigned short* kb  = ws + HSZ;
    unsigned short* vb  = ws + 2 * HSZ;
    unsigned short* ao  = ws + 3 * HSZ;
    unsigned short* xb  = ws + 4 * HSZ;                       // 4096x1024 bf16
    unsigned short* wqb = xb + (size_t)4096 * 1024;           // 3072x1024 bf16
    unsigned short* wpb = wqb + (size_t)3072 * 1024;          // 1024x1024 bf16
    float2* cs = (float2*)(wpb + (size_t)1024 * 1024);        // 2048x32 (cos,sin), 8B-aligned

    prep_kernel<<<2048, 256, 0, stream>>>(x, w_qkv, w_proj, freqs, xb, wqb, wpb, cs);
    qkv_gemm_kernel<<<768, 256, 0, stream>>>(xb, wqb, b_qkv, cs, qb, kb, vb);
    attn_kernel<<<1024, 256, 0, stream>>>(qb, kb, vb, ao);
    proj_kernel<<<512, 256, 0, stream>>>(ao, wpb, b_proj, out);
}

// Round 2
// 200.229 us; speedup vs baseline: 1.2734x; 1.2734x over previous
//
#include <hip/hip_runtime.h>

// Problem constants: B=2, S=2048, D=1024, H=16, HD=64
#define S_LEN 2048
#define NH 16
#define HD 64
#define DMODEL 1024

typedef __bf16 bf16x8 __attribute__((ext_vector_type(8)));
typedef float floatx4 __attribute__((ext_vector_type(4)));
typedef short short8 __attribute__((ext_vector_type(8)));

__device__ inline unsigned short f2bf(float f) {
    union { float f; unsigned u; } v; v.f = f;
    unsigned u = v.u;
    unsigned r = (u + 0x7FFFu + ((u >> 16) & 1u)) >> 16;  // RNE
    return (unsigned short)r;
}

__device__ __forceinline__ void gload_lds16(const void* g, void* l) {
    __builtin_amdgcn_global_load_lds(
        (const __attribute__((address_space(1))) unsigned int*)g,
        (__attribute__((address_space(3))) unsigned int*)l, 16, 0, 0);
}

// ---------------------------------------------------------------------------
// K0: prepass. fp32 -> bf16 for x, w_qkv, w_proj (RNE), and cos/sin table
// for RoPE. Pure streaming, ~50 MB total.
// ---------------------------------------------------------------------------
__device__ __forceinline__ void cvt4(const float4* __restrict__ src,
                                     uint2* __restrict__ dst, int i) {
    float4 v = src[i];
    union { unsigned short u[4]; uint2 d; } o;
    o.u[0] = f2bf(v.x); o.u[1] = f2bf(v.y); o.u[2] = f2bf(v.z); o.u[3] = f2bf(v.w);
    dst[i] = o.d;
}

__global__ __launch_bounds__(256) void prep_kernel(
    const float* __restrict__ x, const float* __restrict__ wq,
    const float* __restrict__ wp, const float* __restrict__ freqs,
    unsigned short* __restrict__ xb, unsigned short* __restrict__ wqb,
    unsigned short* __restrict__ wpb, float2* __restrict__ cs)
{
    const int tid = blockIdx.x * 256 + threadIdx.x;
    const int nth = gridDim.x * 256;
    for (int i = tid; i < (4096 * 1024) / 4; i += nth) cvt4((const float4*)x, (uint2*)xb, i);
    for (int i = tid; i < (3072 * 1024) / 4; i += nth) cvt4((const float4*)wq, (uint2*)wqb, i);
    for (int i = tid; i < (1024 * 1024) / 4; i += nth) cvt4((const float4*)wp, (uint2*)wpb, i);
    for (int i = tid; i < S_LEN * 32; i += nth) {
        const float f = freqs[i];
        float2 c; c.x = cosf(f); c.y = sinf(f);
        cs[i] = c;
    }
}

// Bank swizzle for 32-col (4x16B-chunk) row-major LDS tiles:
//   slot (row, c) holds global chunk c ^ SROW(row); reader of (row, q)
//   reads slot q ^ SROW(row). Makes lanes' b128 frag reads 2-way (free).
#define SROW(r) (((r) & 3) ^ (((r) >> 2) & 3))

// ---------------------------------------------------------------------------
// K1: qkv = x_bf16 @ w_qkv_bf16^T + b_qkv, fused RoPE (table) + scatter.
// 128x128 tile, BK=32, 4 waves (2x2). 2-PHASE PIPELINE (T3 minimum):
// double-buffered LDS, next tile's global_load_lds issued BEFORE current
// tile's ds_read+MFMA, ONE barrier per K-step (vmcnt drain overlapped).
//  q -> [bh][s][hd] row-major, PRE-SCALED by 1/sqrt(HD)=0.125 (exact)
//  k -> blocked [bh][hdblk(8)][s(2048)][8]   (RoPE applied)
//  v -> blocked [bh][sblk(256)][hd(64)][8]   (transposed via LDS tile)
// ---------------------------------------------------------------------------
#define QKV_STAGE(dA, dB, kk) do { \
    gload_lds16(ag + (kk),               (dA) + wv * 512); \
    gload_lds16(ag + 64 * DMODEL + (kk), (dA) + 2048 + wv * 512); \
    gload_lds16(bg + (kk),               (dB) + wv * 512); \
    gload_lds16(bg + 64 * DMODEL + (kk), (dB) + 2048 + wv * 512); \
} while (0)

#define QKV_COMPUTE(sA, sB) do { \
    bf16x8 af[4]; \
    _Pragma("unroll") for (int m_ = 0; m_ < 4; m_++) af[m_] = *(const bf16x8*)&(sA)[aoff[m_]]; \
    _Pragma("unroll") for (int n_ = 0; n_ < 4; n_++) { \
        bf16x8 bf = *(const bf16x8*)&(sB)[boff[n_]]; \
        _Pragma("unroll") for (int m_ = 0; m_ < 4; m_++) \
            acc[m_][n_] = __builtin_amdgcn_mfma_f32_16x16x32_bf16(af[m_], bf, acc[m_][n_], 0, 0, 0); \
    } \
} while (0)

__global__ __launch_bounds__(256, 3) void qkv_gemm_kernel(
    const unsigned short* __restrict__ xb, const unsigned short* __restrict__ wqb,
    const float* __restrict__ bias, const float2* __restrict__ cs,
    unsigned short* __restrict__ qb, unsigned short* __restrict__ kb,
    unsigned short* __restrict__ vb)
{
    // dbuf: buf b at smem + b*8192 (A 4096 shorts, B 4096 shorts).
    // V epilogue reuses smem as 128x72 tile (9216 shorts <= 16384).
    __shared__ __align__(16) unsigned short smem[16384];
    unsigned short* A0 = smem;
    unsigned short* B0 = smem + 4096;
    unsigned short* A1 = smem + 8192;
    unsigned short* B1 = smem + 12288;

    const int t = threadIdx.x;
    // XCD swizzle (768 % 8 == 0): each XCD owns 4 contiguous m-panels.
    const int v = (blockIdx.x & 7) * 96 + (blockIdx.x >> 3);
    const int mbase = (v / 24) * 128;   // 32 m-tiles
    const int nbase = (v % 24) * 128;   // 24 n-tiles
    const int wv = t >> 6, lane = t & 63;
    const int quad = lane >> 4, l16 = lane & 15;
    const int wr = wv >> 1, wc = wv & 1;

    floatx4 acc[4][4];
    #pragma unroll
    for (int m = 0; m < 4; m++)
        #pragma unroll
        for (int n = 0; n < 4; n++)
            #pragma unroll
            for (int r = 0; r < 4; r++) acc[m][n][r] = 0.f;

    // staging: thread t owns LDS 16B slot t (row t>>2, chunk t&3); source
    // chunk pre-swizzled so LDS slot (row,c) holds global chunk c^SROW(row).
    const int srow = t >> 2;
    const int schunk = (t & 3) ^ SROW(srow);
    const unsigned short* ag = xb + (size_t)(mbase + srow) * DMODEL + schunk * 8;
    const unsigned short* bg = wqb + (size_t)(nbase + srow) * DMODEL + schunk * 8;

    const int Sl = SROW(l16);           // == SROW(row) for all frag rows
    int aoff[4], boff[4];
    #pragma unroll
    for (int m = 0; m < 4; m++) aoff[m] = (wr * 64 + m * 16 + l16) * 32 + (quad ^ Sl) * 8;
    #pragma unroll
    for (int n = 0; n < 4; n++) boff[n] = (wc * 64 + n * 16 + l16) * 32 + (quad ^ Sl) * 8;

    QKV_STAGE(A0, B0, 0);
    __syncthreads();                    // prologue drain
    for (int k0 = 0; k0 < DMODEL; k0 += 64) {
        QKV_STAGE(A1, B1, k0 + 32);     // issue next tile first
        QKV_COMPUTE(A0, B0);            // latency hidden under this
        __syncthreads();                // drain (loads landed) + sync
        if (k0 + 64 < DMODEL) QKV_STAGE(A0, B0, k0 + 64);
        QKV_COMPUTE(A1, B1);
        __syncthreads();
    }

    // n-tile is 128 cols: never crosses a q/k/v part boundary, spans 2 heads.
    const int part = nbase >> 10;                 // 0=q 1=k 2=v
    const int bidx = mbase >> 11;
    const int s0   = mbase & 2047;

    if (part == 2) {
        // ---- V: bias, transpose 128(s) x 128(hd) tile via LDS in two s-halves
        unsigned short* Vt = smem;                // 128 hd x 72 s-pad
        const int hb = (nbase & 1023) >> 6;       // base head
        float bvv[4];
        #pragma unroll
        for (int nt = 0; nt < 4; nt++) bvv[nt] = bias[nbase + wc * 64 + nt * 16 + l16];
        #pragma unroll
        for (int shalf = 0; shalf < 2; shalf++) {
            __syncthreads();
            if (wr == shalf) {
                #pragma unroll
                for (int nt = 0; nt < 4; nt++) {
                    const int hdl = wc * 64 + nt * 16 + l16;
                    #pragma unroll
                    for (int m = 0; m < 4; m++)
                        #pragma unroll
                        for (int r = 0; r < 4; r++)
                            Vt[hdl * 72 + m * 16 + quad * 4 + r] = f2bf(acc[m][nt][r] + bvv[nt]);
                }
            }
            __syncthreads();
            const int hdl = t & 127, sp = t >> 7;
            const size_t bh2 = (size_t)bidx * NH + hb + (hdl >> 6);
            #pragma unroll
            for (int c = 0; c < 4; c++) {
                const int sl0 = (sp * 4 + c) * 8;
                const int sg = s0 + shalf * 64 + sl0;
                short8 vv = *(const short8*)&Vt[hdl * 72 + sl0];
                *(short8*)&vb[((bh2 * 256 + (sg >> 3)) * 64 + (hdl & 63)) * 8] = vv;
            }
        }
    } else {
        // ---- Q/K: bias + RoPE from table. Pair = adjacent col = adjacent l16.
        const size_t bhb = (size_t)bidx * NH;
        const int odd = l16 & 1;
        #pragma unroll
        for (int nt = 0; nt < 4; nt++) {
            const int n_ = nbase + wc * 64 + nt * 16 + l16;
            const int hd = n_ & 63;
            const size_t bh = bhb + ((n_ & 1023) >> 6);
            const float bvv = bias[n_];
            const int ci = (nt * 16 + l16) >> 1;
            #pragma unroll
            for (int m = 0; m < 4; m++) {
                #pragma unroll
                for (int r = 0; r < 4; r++) {
                    const int s = s0 + wr * 64 + m * 16 + quad * 4 + r;
                    float val = acc[m][nt][r] + bvv;
                    float other = __shfl_xor(val, 1, 64);
                    const float2 csv = cs[(size_t)s * 32 + ci];
                    float outv = odd ? fmaf(other, csv.y, val * csv.x)
                                     : fmaf(-other, csv.y, val * csv.x);
                    if (part == 0) {
                        qb[(bh * S_LEN + s) * HD + hd] = f2bf(outv * 0.125f);
                    } else {
                        kb[((bh * 8 + (hd >> 3)) * (size_t)S_LEN + s) * 8 + (hd & 7)] = f2bf(outv);
                    }
                }
            }
        }
    }
}

// ---------------------------------------------------------------------------
// K2: causal flash attention (unchanged this round).
// ---------------------------------------------------------------------------
__global__ __launch_bounds__(256, 4) void attn_kernel(
    const unsigned short* __restrict__ qb, const unsigned short* __restrict__ kb,
    const unsigned short* __restrict__ vbk, unsigned short* __restrict__ ao)
{
    __shared__ __align__(16) unsigned short Ks[8 * 512];
    __shared__ __align__(16) unsigned short Vt[8 * 512];
    __shared__ __align__(16) unsigned short Pw[4][16 * 72];

    const int t = threadIdx.x;
    const int wv = t >> 6, lane = t & 63, quad = lane >> 4, l16 = lane & 15;
    const int qt   = blockIdx.x >> 5;
    const int bhid = blockIdx.x & 31;
    const int h = bhid & 15, b = bhid >> 4;
    const size_t bh = (size_t)b * NH + h;
    const unsigned short* qg  = qb + bh * S_LEN * HD;
    const unsigned short* kgB = kb + bh * 8 * S_LEN * 8;
    const unsigned short* vgB = vbk + bh * 256 * 64 * 8;

    bf16x8 qf[2];
    {
        const unsigned short* q0 = qg + (size_t)(qt * 64 + wv * 16 + l16) * HD;
        qf[0] = *(const bf16x8*)&q0[quad * 8];
        qf[1] = *(const bf16x8*)&q0[32 + quad * 8];
    }

    bf16x8 ones;
    {
        union { short8 s; bf16x8 v; } o;
        for (int j = 0; j < 8; j++) o.s[j] = 0x3F80;
        ones = o.v;
    }

    floatx4 lfr = {0.f, 0.f, 0.f, 0.f};
    floatx4 Ofr[4];
    for (int nt = 0; nt < 4; nt++)
        for (int r = 0; r < 4; r++) Ofr[nt][r] = 0.f;

    const int ntiles = qt + 1;

    for (int kt = 0; kt < ntiles; kt++) {
        const int kbase = kt * 64;
        {
            const unsigned short* g0 = kgB + ((size_t)(2 * wv) * S_LEN + kbase + lane) * 8;
            gload_lds16(g0,             &Ks[(2 * wv) * 512]);
            gload_lds16(g0 + S_LEN * 8, &Ks[(2 * wv + 1) * 512]);
            const unsigned short* g1 = vgB + ((size_t)((kbase >> 3) + 2 * wv) * 64 + lane) * 8;
            gload_lds16(g1,          &Vt[(2 * wv) * 512]);
            gload_lds16(g1 + 64 * 8, &Vt[(2 * wv + 1) * 512]);
        }
        __syncthreads();

        float pex[4][4];
        #pragma unroll
        for (int sub = 0; sub < 4; sub++) {
            bf16x8 kf0 = *(const bf16x8*)&Ks[(0 * 4 + quad) * 512 + (sub * 16 + l16) * 8];
            bf16x8 kf1 = *(const bf16x8*)&Ks[(1 * 4 + quad) * 512 + (sub * 16 + l16) * 8];
            floatx4 sacc = {0.f, 0.f, 0.f, 0.f};
            sacc = __builtin_amdgcn_mfma_f32_16x16x32_bf16(kf0, qf[0], sacc, 0, 0, 0);
            sacc = __builtin_amdgcn_mfma_f32_16x16x32_bf16(kf1, qf[1], sacc, 0, 0, 0);
            #pragma unroll
            for (int r = 0; r < 4; r++) pex[sub][r] = sacc[r];
        }
        if (kt == qt) {
            const int q = qt * 64 + wv * 16 + l16;
            #pragma unroll
            for (int sub = 0; sub < 4; sub++)
                #pragma unroll
                for (int r = 0; r < 4; r++) {
                    const int key = kbase + sub * 16 + quad * 4 + r;
                    if (key > q) pex[sub][r] = -1e30f;
                }
        }
        #pragma unroll
        for (int sub = 0; sub < 4; sub++) {
            union { unsigned short s[4]; uint2 u; } pk;
            #pragma unroll
            for (int r = 0; r < 4; r++) pk.s[r] = f2bf(__expf(pex[sub][r]));
            *(uint2*)&Pw[wv][l16 * 72 + sub * 16 + quad * 4] = pk.u;
        }
        bf16x8 pf0 = *(const bf16x8*)&Pw[wv][l16 * 72 + quad * 8];
        bf16x8 pf1 = *(const bf16x8*)&Pw[wv][l16 * 72 + 32 + quad * 8];
        lfr = __builtin_amdgcn_mfma_f32_16x16x32_bf16(ones, pf0, lfr, 0, 0, 0);
        lfr = __builtin_amdgcn_mfma_f32_16x16x32_bf16(ones, pf1, lfr, 0, 0, 0);
        #pragma unroll
        for (int nt = 0; nt < 4; nt++) {
            bf16x8 v0 = *(const bf16x8*)&Vt[(0 * 4 + quad) * 512 + (nt * 16 + l16) * 8];
            bf16x8 v1 = *(const bf16x8*)&Vt[(1 * 4 + quad) * 512 + (nt * 16 + l16) * 8];
            Ofr[nt] = __builtin_amdgcn_mfma_f32_16x16x32_bf16(pf0, v0, Ofr[nt], 0, 0, 0);
            Ofr[nt] = __builtin_amdgcn_mfma_f32_16x16x32_bf16(pf1, v1, Ofr[nt], 0, 0, 0);
        }
        __syncthreads();
    }

    float linv[4];
    #pragma unroll
    for (int r = 0; r < 4; r++) {
        float lq = __shfl(lfr[0], (lane & 48) | (quad * 4 + r), 64);
        linv[r] = 1.f / lq;
    }
    #pragma unroll
    for (int nt = 0; nt < 4; nt++)
        #pragma unroll
        for (int r = 0; r < 4; r++) {
            const int s = qt * 64 + wv * 16 + quad * 4 + r;
            ao[((size_t)b * S_LEN + s) * DMODEL + h * HD + nt * 16 + l16] =
                f2bf(Ofr[nt][r] * linv[r]);
        }
}

// ---------------------------------------------------------------------------
// K3: out = ao @ w_proj_bf16^T + b_proj.  M=4096, N=1024, K=1024. fp32 out.
// 128x64 tile, 2-phase pipeline, dbuf LDS, grid 512 (2/CU), XCD swizzle.
// ---------------------------------------------------------------------------
#define PROJ_STAGE(dA, dB, kk) do { \
    gload_lds16(ag + (kk),               (dA) + wv * 512); \
    gload_lds16(ag + 64 * DMODEL + (kk), (dA) + 2048 + wv * 512); \
    gload_lds16(bg + (kk),               (dB) + wv * 512); \
} while (0)

#define PROJ_COMPUTE(sA, sB) do { \
    bf16x8 af[4]; \
    _Pragma("unroll") for (int m_ = 0; m_ < 4; m_++) af[m_] = *(const bf16x8*)&(sA)[aoff[m_]]; \
    _Pragma("unroll") for (int n_ = 0; n_ < 2; n_++) { \
        bf16x8 bf = *(const bf16x8*)&(sB)[boff[n_]]; \
        _Pragma("unroll") for (int m_ = 0; m_ < 4; m_++) \
            acc[m_][n_] = __builtin_amdgcn_mfma_f32_16x16x32_bf16(af[m_], bf, acc[m_][n_], 0, 0, 0); \
    } \
} while (0)

__global__ __launch_bounds__(256, 3) void proj_kernel(
    const unsigned short* __restrict__ a, const unsigned short* __restrict__ wpb,
    const float* __restrict__ bias, float* __restrict__ out)
{
    // dbuf: buf b at smem + b*6144 (A 4096 shorts, B 2048 shorts)
    __shared__ __align__(16) unsigned short smem[12288];
    unsigned short* A0 = smem;
    unsigned short* B0 = smem + 4096;
    unsigned short* A1 = smem + 6144;
    unsigned short* B1 = smem + 10240;

    const int t = threadIdx.x;
    const int v = (blockIdx.x & 7) * 64 + (blockIdx.x >> 3);
    const int mbase = (v >> 4) * 128;   // 32 m-tiles
    const int nbase = (v & 15) * 64;    // 16 n-tiles
    const int wv = t >> 6, lane = t & 63, quad = lane >> 4, l16 = lane & 15;
    const int wr = wv >> 1, wc = wv & 1;

    floatx4 acc[4][2];
    #pragma unroll
    for (int m = 0; m < 4; m++)
        #pragma unroll
        for (int n = 0; n < 2; n++)
            #pragma unroll
            for (int r = 0; r < 4; r++) acc[m][n][r] = 0.f;

    const int srow = t >> 2;
    const int schunk = (t & 3) ^ SROW(srow);
    const unsigned short* ag = a + (size_t)(mbase + srow) * DMODEL + schunk * 8;
    const unsigned short* bg = wpb + (size_t)(nbase + srow) * DMODEL + schunk * 8;

    const int Sl = SROW(l16);
    int aoff[4], boff[2];
    #pragma unroll
    for (int m = 0; m < 4; m++) aoff[m] = (wr * 64 + m * 16 + l16) * 32 + (quad ^ Sl) * 8;
    #pragma unroll
    for (int n = 0; n < 2; n++) boff[n] = (wc * 32 + n * 16 + l16) * 32 + (quad ^ Sl) * 8;

    PROJ_STAGE(A0, B0, 0);
    __syncthreads();
    for (int k0 = 0; k0 < DMODEL; k0 += 64) {
        PROJ_STAGE(A1, B1, k0 + 32);
        PROJ_COMPUTE(A0, B0);
        __syncthreads();
        if (k0 + 64 < DMODEL) PROJ_STAGE(A0, B0, k0 + 64);
        PROJ_COMPUTE(A1, B1);
        __syncthreads();
    }

    #pragma unroll
    for (int n = 0; n < 2; n++) {
        const int nn = nbase + wc * 32 + n * 16 + l16;
        const float bvv = bias[nn];
        #pragma unroll
        for (int m = 0; m < 4; m++)
            #pragma unroll
            for (int r = 0; r < 4; r++)
                out[(size_t)(mbase + wr * 64 + m * 16 + quad * 4 + r) * DMODEL + nn] =
                    acc[m][n][r] + bvv;
    }
}

extern "C" void kernel_launch(void* const* d_in, const int* in_sizes, int n_in,
                              void* d_out, int out_size, void* d_ws, size_t ws_size,
                              hipStream_t stream) {
    const float* x      = (const float*)d_in[0];
    const float* freqs  = (const float*)d_in[2];
    const float* w_qkv  = (const float*)d_in[3];
    const float* b_qkv  = (const float*)d_in[4];
    const float* w_proj = (const float*)d_in[5];
    const float* b_proj = (const float*)d_in[6];
    float* out = (float*)d_out;

    unsigned short* ws = (unsigned short*)d_ws;
    const size_t HSZ = (size_t)2 * NH * S_LEN * HD;   // 4,194,304 shorts
    unsigned short* qb  = ws;
    unsigned short* kb  = ws + HSZ;
    unsigned short* vb  = ws + 2 * HSZ;
    unsigned short* ao  = ws + 3 * HSZ;
    unsigned short* xb  = ws + 4 * HSZ;                       // 4096x1024 bf16
    unsigned short* wqb = xb + (size_t)4096 * 1024;           // 3072x1024 bf16
    unsigned short* wpb = wqb + (size_t)3072 * 1024;          // 1024x1024 bf16
    float2* cs = (float2*)(wpb + (size_t)1024 * 1024);        // 2048x32 (cos,sin)

    prep_kernel<<<2048, 256, 0, stream>>>(x, w_qkv, w_proj, freqs, xb, wqb, wpb, cs);
    qkv_gemm_kernel<<<768, 256, 0, stream>>>(xb, wqb, b_qkv, cs, qb, kb, vb);
    attn_kernel<<<1024, 256, 0, stream>>>(qb, kb, vb, ao);
    proj_kernel<<<512, 256, 0, stream>>>(ao, wpb, b_proj, out);
}

// Round 3
// 192.336 us; speedup vs baseline: 1.3257x; 1.0410x over previous
//
#include <hip/hip_runtime.h>

// Problem constants: B=2, S=2048, D=1024, H=16, HD=64
#define S_LEN 2048
#define NH 16
#define HD 64
#define DMODEL 1024

typedef __bf16 bf16x8 __attribute__((ext_vector_type(8)));
typedef float floatx4 __attribute__((ext_vector_type(4)));
typedef short short8 __attribute__((ext_vector_type(8)));

__device__ inline unsigned short f2bf(float f) {
    union { float f; unsigned u; } v; v.f = f;
    unsigned u = v.u;
    unsigned r = (u + 0x7FFFu + ((u >> 16) & 1u)) >> 16;  // RNE
    return (unsigned short)r;
}

__device__ __forceinline__ void gload_lds16(const void* g, void* l) {
    __builtin_amdgcn_global_load_lds(
        (const __attribute__((address_space(1))) unsigned int*)g,
        (__attribute__((address_space(3))) unsigned int*)l, 16, 0, 0);
}

// ---------------------------------------------------------------------------
// K0: prepass. fp32 -> bf16 for x, w_qkv, w_proj (RNE), and cos/sin table.
// ---------------------------------------------------------------------------
__device__ __forceinline__ void cvt4(const float4* __restrict__ src,
                                     uint2* __restrict__ dst, int i) {
    float4 v = src[i];
    union { unsigned short u[4]; uint2 d; } o;
    o.u[0] = f2bf(v.x); o.u[1] = f2bf(v.y); o.u[2] = f2bf(v.z); o.u[3] = f2bf(v.w);
    dst[i] = o.d;
}

__global__ __launch_bounds__(256) void prep_kernel(
    const float* __restrict__ x, const float* __restrict__ wq,
    const float* __restrict__ wp, const float* __restrict__ freqs,
    unsigned short* __restrict__ xb, unsigned short* __restrict__ wqb,
    unsigned short* __restrict__ wpb, float2* __restrict__ cs)
{
    const int tid = blockIdx.x * 256 + threadIdx.x;
    const int nth = gridDim.x * 256;
    for (int i = tid; i < (4096 * 1024) / 4; i += nth) cvt4((const float4*)x, (uint2*)xb, i);
    for (int i = tid; i < (3072 * 1024) / 4; i += nth) cvt4((const float4*)wq, (uint2*)wqb, i);
    for (int i = tid; i < (1024 * 1024) / 4; i += nth) cvt4((const float4*)wp, (uint2*)wpb, i);
    for (int i = tid; i < S_LEN * 32; i += nth) {
        const float f = freqs[i];
        float2 c; c.x = cosf(f); c.y = sinf(f);
        cs[i] = c;
    }
}

// Bank swizzle for 32-col (4x16B-chunk) row-major LDS tiles (neutral on
// conflicts per R2 counters, kept: cost-free and proven correct).
#define SROW(r) (((r) & 3) ^ (((r) >> 2) & 3))

// ---------------------------------------------------------------------------
// K1: qkv = x_bf16 @ w_qkv_bf16^T + b_qkv, fused RoPE (table) + scatter.
// 128x128 tile, BK=32, 2-phase dbuf pipeline. (unchanged from R2)
// ---------------------------------------------------------------------------
#define QKV_STAGE(dA, dB, kk) do { \
    gload_lds16(ag + (kk),               (dA) + wv * 512); \
    gload_lds16(ag + 64 * DMODEL + (kk), (dA) + 2048 + wv * 512); \
    gload_lds16(bg + (kk),               (dB) + wv * 512); \
    gload_lds16(bg + 64 * DMODEL + (kk), (dB) + 2048 + wv * 512); \
} while (0)

#define QKV_COMPUTE(sA, sB) do { \
    bf16x8 af[4]; \
    _Pragma("unroll") for (int m_ = 0; m_ < 4; m_++) af[m_] = *(const bf16x8*)&(sA)[aoff[m_]]; \
    _Pragma("unroll") for (int n_ = 0; n_ < 4; n_++) { \
        bf16x8 bf = *(const bf16x8*)&(sB)[boff[n_]]; \
        _Pragma("unroll") for (int m_ = 0; m_ < 4; m_++) \
            acc[m_][n_] = __builtin_amdgcn_mfma_f32_16x16x32_bf16(af[m_], bf, acc[m_][n_], 0, 0, 0); \
    } \
} while (0)

__global__ __launch_bounds__(256, 3) void qkv_gemm_kernel(
    const unsigned short* __restrict__ xb, const unsigned short* __restrict__ wqb,
    const float* __restrict__ bias, const float2* __restrict__ cs,
    unsigned short* __restrict__ qb, unsigned short* __restrict__ kb,
    unsigned short* __restrict__ vb)
{
    __shared__ __align__(16) unsigned short smem[16384];
    unsigned short* A0 = smem;
    unsigned short* B0 = smem + 4096;
    unsigned short* A1 = smem + 8192;
    unsigned short* B1 = smem + 12288;

    const int t = threadIdx.x;
    const int v = (blockIdx.x & 7) * 96 + (blockIdx.x >> 3);
    const int mbase = (v / 24) * 128;   // 32 m-tiles
    const int nbase = (v % 24) * 128;   // 24 n-tiles
    const int wv = t >> 6, lane = t & 63;
    const int quad = lane >> 4, l16 = lane & 15;
    const int wr = wv >> 1, wc = wv & 1;

    floatx4 acc[4][4];
    #pragma unroll
    for (int m = 0; m < 4; m++)
        #pragma unroll
        for (int n = 0; n < 4; n++)
            #pragma unroll
            for (int r = 0; r < 4; r++) acc[m][n][r] = 0.f;

    const int srow = t >> 2;
    const int schunk = (t & 3) ^ SROW(srow);
    const unsigned short* ag = xb + (size_t)(mbase + srow) * DMODEL + schunk * 8;
    const unsigned short* bg = wqb + (size_t)(nbase + srow) * DMODEL + schunk * 8;

    const int Sl = SROW(l16);
    int aoff[4], boff[4];
    #pragma unroll
    for (int m = 0; m < 4; m++) aoff[m] = (wr * 64 + m * 16 + l16) * 32 + (quad ^ Sl) * 8;
    #pragma unroll
    for (int n = 0; n < 4; n++) boff[n] = (wc * 64 + n * 16 + l16) * 32 + (quad ^ Sl) * 8;

    QKV_STAGE(A0, B0, 0);
    __syncthreads();
    for (int k0 = 0; k0 < DMODEL; k0 += 64) {
        QKV_STAGE(A1, B1, k0 + 32);
        QKV_COMPUTE(A0, B0);
        __syncthreads();
        if (k0 + 64 < DMODEL) QKV_STAGE(A0, B0, k0 + 64);
        QKV_COMPUTE(A1, B1);
        __syncthreads();
    }

    const int part = nbase >> 10;                 // 0=q 1=k 2=v
    const int bidx = mbase >> 11;
    const int s0   = mbase & 2047;

    if (part == 2) {
        unsigned short* Vt = smem;                // 128 hd x 72 s-pad
        const int hb = (nbase & 1023) >> 6;
        float bvv[4];
        #pragma unroll
        for (int nt = 0; nt < 4; nt++) bvv[nt] = bias[nbase + wc * 64 + nt * 16 + l16];
        #pragma unroll
        for (int shalf = 0; shalf < 2; shalf++) {
            __syncthreads();
            if (wr == shalf) {
                #pragma unroll
                for (int nt = 0; nt < 4; nt++) {
                    const int hdl = wc * 64 + nt * 16 + l16;
                    #pragma unroll
                    for (int m = 0; m < 4; m++)
                        #pragma unroll
                        for (int r = 0; r < 4; r++)
                            Vt[hdl * 72 + m * 16 + quad * 4 + r] = f2bf(acc[m][nt][r] + bvv[nt]);
                }
            }
            __syncthreads();
            const int hdl = t & 127, sp = t >> 7;
            const size_t bh2 = (size_t)bidx * NH + hb + (hdl >> 6);
            #pragma unroll
            for (int c = 0; c < 4; c++) {
                const int sl0 = (sp * 4 + c) * 8;
                const int sg = s0 + shalf * 64 + sl0;
                short8 vv = *(const short8*)&Vt[hdl * 72 + sl0];
                *(short8*)&vb[((bh2 * 256 + (sg >> 3)) * 64 + (hdl & 63)) * 8] = vv;
            }
        }
    } else {
        const size_t bhb = (size_t)bidx * NH;
        const int odd = l16 & 1;
        #pragma unroll
        for (int nt = 0; nt < 4; nt++) {
            const int n_ = nbase + wc * 64 + nt * 16 + l16;
            const int hd = n_ & 63;
            const size_t bh = bhb + ((n_ & 1023) >> 6);
            const float bvv = bias[n_];
            const int ci = (nt * 16 + l16) >> 1;
            #pragma unroll
            for (int m = 0; m < 4; m++) {
                #pragma unroll
                for (int r = 0; r < 4; r++) {
                    const int s = s0 + wr * 64 + m * 16 + quad * 4 + r;
                    float val = acc[m][nt][r] + bvv;
                    float other = __shfl_xor(val, 1, 64);
                    const float2 csv = cs[(size_t)s * 32 + ci];
                    float outv = odd ? fmaf(other, csv.y, val * csv.x)
                                     : fmaf(-other, csv.y, val * csv.x);
                    if (part == 0) {
                        qb[(bh * S_LEN + s) * HD + hd] = f2bf(outv * 0.125f);
                    } else {
                        kb[((bh * 8 + (hd >> 3)) * (size_t)S_LEN + s) * 8 + (hd & 7)] = f2bf(outv);
                    }
                }
            }
        }
    }
}

// ---------------------------------------------------------------------------
// K2: causal flash attention. NEW: 2-phase double-buffered K/V staging
// (prefetch kt+1 issued before compute of kt -> vmcnt drain covered by a
// full tile of MFMA+exp work; ONE barrier per tile, was two) + reversed
// qt launch order (long blocks first, kills triangular tail).
// LDS 41KB -> 3 blocks/CU.
// ---------------------------------------------------------------------------
__global__ __launch_bounds__(256, 3) void attn_kernel(
    const unsigned short* __restrict__ qb, const unsigned short* __restrict__ kb,
    const unsigned short* __restrict__ vbk, unsigned short* __restrict__ ao)
{
    __shared__ __align__(16) unsigned short Ks[2][8 * 512];
    __shared__ __align__(16) unsigned short Vt[2][8 * 512];
    __shared__ __align__(16) unsigned short Pw[4][16 * 72];

    const int t = threadIdx.x;
    const int wv = t >> 6, lane = t & 63, quad = lane >> 4, l16 = lane & 15;
    const int qt   = 31 - (blockIdx.x >> 5);      // reversed: long blocks first
    const int bhid = blockIdx.x & 31;
    const int h = bhid & 15, b = bhid >> 4;
    const size_t bh = (size_t)b * NH + h;
    const unsigned short* qg  = qb + bh * S_LEN * HD;
    const unsigned short* kgB = kb + bh * 8 * S_LEN * 8;
    const unsigned short* vgB = vbk + bh * 256 * 64 * 8;

    bf16x8 qf[2];
    {
        const unsigned short* q0 = qg + (size_t)(qt * 64 + wv * 16 + l16) * HD;
        qf[0] = *(const bf16x8*)&q0[quad * 8];
        qf[1] = *(const bf16x8*)&q0[32 + quad * 8];
    }

    bf16x8 ones;
    {
        union { short8 s; bf16x8 v; } o;
        for (int j = 0; j < 8; j++) o.s[j] = 0x3F80;
        ones = o.v;
    }

    floatx4 lfr = {0.f, 0.f, 0.f, 0.f};
    floatx4 Ofr[4];
    for (int nt = 0; nt < 4; nt++)
        for (int r = 0; r < 4; r++) Ofr[nt][r] = 0.f;

    const int ntiles = qt + 1;

#define ATTN_STAGE(bufi, kt_) do { \
    const int kb_ = (kt_) * 64; \
    const unsigned short* g0 = kgB + ((size_t)(2 * wv) * S_LEN + kb_ + lane) * 8; \
    gload_lds16(g0,             &Ks[bufi][(2 * wv) * 512]); \
    gload_lds16(g0 + S_LEN * 8, &Ks[bufi][(2 * wv + 1) * 512]); \
    const unsigned short* g1 = vgB + ((size_t)((kb_ >> 3) + 2 * wv) * 64 + lane) * 8; \
    gload_lds16(g1,          &Vt[bufi][(2 * wv) * 512]); \
    gload_lds16(g1 + 64 * 8, &Vt[bufi][(2 * wv + 1) * 512]); \
} while (0)

#define ATTN_COMPUTE(bufi, kt_) do { \
    const int kbase = (kt_) * 64; \
    float pex[4][4]; \
    _Pragma("unroll") for (int sub = 0; sub < 4; sub++) { \
        bf16x8 kf0 = *(const bf16x8*)&Ks[bufi][(0 * 4 + quad) * 512 + (sub * 16 + l16) * 8]; \
        bf16x8 kf1 = *(const bf16x8*)&Ks[bufi][(1 * 4 + quad) * 512 + (sub * 16 + l16) * 8]; \
        floatx4 sacc = {0.f, 0.f, 0.f, 0.f}; \
        sacc = __builtin_amdgcn_mfma_f32_16x16x32_bf16(kf0, qf[0], sacc, 0, 0, 0); \
        sacc = __builtin_amdgcn_mfma_f32_16x16x32_bf16(kf1, qf[1], sacc, 0, 0, 0); \
        _Pragma("unroll") for (int r = 0; r < 4; r++) pex[sub][r] = sacc[r]; \
    } \
    if ((kt_) == qt) { \
        const int q = qt * 64 + wv * 16 + l16; \
        _Pragma("unroll") for (int sub = 0; sub < 4; sub++) \
            _Pragma("unroll") for (int r = 0; r < 4; r++) { \
                const int key = kbase + sub * 16 + quad * 4 + r; \
                if (key > q) pex[sub][r] = -1e30f; \
            } \
    } \
    _Pragma("unroll") for (int sub = 0; sub < 4; sub++) { \
        union { unsigned short s[4]; uint2 u; } pk; \
        _Pragma("unroll") for (int r = 0; r < 4; r++) pk.s[r] = f2bf(__expf(pex[sub][r])); \
        *(uint2*)&Pw[wv][l16 * 72 + sub * 16 + quad * 4] = pk.u; \
    } \
    { \
        bf16x8 pf0 = *(const bf16x8*)&Pw[wv][l16 * 72 + quad * 8]; \
        bf16x8 pf1 = *(const bf16x8*)&Pw[wv][l16 * 72 + 32 + quad * 8]; \
        lfr = __builtin_amdgcn_mfma_f32_16x16x32_bf16(ones, pf0, lfr, 0, 0, 0); \
        lfr = __builtin_amdgcn_mfma_f32_16x16x32_bf16(ones, pf1, lfr, 0, 0, 0); \
        _Pragma("unroll") for (int nt = 0; nt < 4; nt++) { \
            bf16x8 v0 = *(const bf16x8*)&Vt[bufi][(0 * 4 + quad) * 512 + (nt * 16 + l16) * 8]; \
            bf16x8 v1 = *(const bf16x8*)&Vt[bufi][(1 * 4 + quad) * 512 + (nt * 16 + l16) * 8]; \
            Ofr[nt] = __builtin_amdgcn_mfma_f32_16x16x32_bf16(pf0, v0, Ofr[nt], 0, 0, 0); \
            Ofr[nt] = __builtin_amdgcn_mfma_f32_16x16x32_bf16(pf1, v1, Ofr[nt], 0, 0, 0); \
        } \
    } \
} while (0)

    ATTN_STAGE(0, 0);
    __syncthreads();
    for (int kt = 0; kt < ntiles; ) {
        if (kt + 1 < ntiles) ATTN_STAGE(1, kt + 1);
        ATTN_COMPUTE(0, kt);
        kt++;
        if (kt >= ntiles) break;
        __syncthreads();
        if (kt + 1 < ntiles) ATTN_STAGE(0, kt + 1);
        ATTN_COMPUTE(1, kt);
        kt++;
        if (kt >= ntiles) break;
        __syncthreads();
    }

    float linv[4];
    #pragma unroll
    for (int r = 0; r < 4; r++) {
        float lq = __shfl(lfr[0], (lane & 48) | (quad * 4 + r), 64);
        linv[r] = 1.f / lq;
    }
    #pragma unroll
    for (int nt = 0; nt < 4; nt++)
        #pragma unroll
        for (int r = 0; r < 4; r++) {
            const int s = qt * 64 + wv * 16 + quad * 4 + r;
            ao[((size_t)b * S_LEN + s) * DMODEL + h * HD + nt * 16 + l16] =
                f2bf(Ofr[nt][r] * linv[r]);
        }
#undef ATTN_STAGE
#undef ATTN_COMPUTE
}

// ---------------------------------------------------------------------------
// K3: out = ao @ w_proj_bf16^T + b_proj. (unchanged from R2)
// ---------------------------------------------------------------------------
#define PROJ_STAGE(dA, dB, kk) do { \
    gload_lds16(ag + (kk),               (dA) + wv * 512); \
    gload_lds16(ag + 64 * DMODEL + (kk), (dA) + 2048 + wv * 512); \
    gload_lds16(bg + (kk),               (dB) + wv * 512); \
} while (0)

#define PROJ_COMPUTE(sA, sB) do { \
    bf16x8 af[4]; \
    _Pragma("unroll") for (int m_ = 0; m_ < 4; m_++) af[m_] = *(const bf16x8*)&(sA)[aoff[m_]]; \
    _Pragma("unroll") for (int n_ = 0; n_ < 2; n_++) { \
        bf16x8 bf = *(const bf16x8*)&(sB)[boff[n_]]; \
        _Pragma("unroll") for (int m_ = 0; m_ < 4; m_++) \
            acc[m_][n_] = __builtin_amdgcn_mfma_f32_16x16x32_bf16(af[m_], bf, acc[m_][n_], 0, 0, 0); \
    } \
} while (0)

__global__ __launch_bounds__(256, 3) void proj_kernel(
    const unsigned short* __restrict__ a, const unsigned short* __restrict__ wpb,
    const float* __restrict__ bias, float* __restrict__ out)
{
    __shared__ __align__(16) unsigned short smem[12288];
    unsigned short* A0 = smem;
    unsigned short* B0 = smem + 4096;
    unsigned short* A1 = smem + 6144;
    unsigned short* B1 = smem + 10240;

    const int t = threadIdx.x;
    const int v = (blockIdx.x & 7) * 64 + (blockIdx.x >> 3);
    const int mbase = (v >> 4) * 128;
    const int nbase = (v & 15) * 64;
    const int wv = t >> 6, lane = t & 63, quad = lane >> 4, l16 = lane & 15;
    const int wr = wv >> 1, wc = wv & 1;

    floatx4 acc[4][2];
    #pragma unroll
    for (int m = 0; m < 4; m++)
        #pragma unroll
        for (int n = 0; n < 2; n++)
            #pragma unroll
            for (int r = 0; r < 4; r++) acc[m][n][r] = 0.f;

    const int srow = t >> 2;
    const int schunk = (t & 3) ^ SROW(srow);
    const unsigned short* ag = a + (size_t)(mbase + srow) * DMODEL + schunk * 8;
    const unsigned short* bg = wpb + (size_t)(nbase + srow) * DMODEL + schunk * 8;

    const int Sl = SROW(l16);
    int aoff[4], boff[2];
    #pragma unroll
    for (int m = 0; m < 4; m++) aoff[m] = (wr * 64 + m * 16 + l16) * 32 + (quad ^ Sl) * 8;
    #pragma unroll
    for (int n = 0; n < 2; n++) boff[n] = (wc * 32 + n * 16 + l16) * 32 + (quad ^ Sl) * 8;

    PROJ_STAGE(A0, B0, 0);
    __syncthreads();
    for (int k0 = 0; k0 < DMODEL; k0 += 64) {
        PROJ_STAGE(A1, B1, k0 + 32);
        PROJ_COMPUTE(A0, B0);
        __syncthreads();
        if (k0 + 64 < DMODEL) PROJ_STAGE(A0, B0, k0 + 64);
        PROJ_COMPUTE(A1, B1);
        __syncthreads();
    }

    #pragma unroll
    for (int n = 0; n < 2; n++) {
        const int nn = nbase + wc * 32 + n * 16 + l16;
        const float bvv = bias[nn];
        #pragma unroll
        for (int m = 0; m < 4; m++)
            #pragma unroll
            for (int r = 0; r < 4; r++)
                out[(size_t)(mbase + wr * 64 + m * 16 + quad * 4 + r) * DMODEL + nn] =
                    acc[m][n][r] + bvv;
    }
}

extern "C" void kernel_launch(void* const* d_in, const int* in_sizes, int n_in,
                              void* d_out, int out_size, void* d_ws, size_t ws_size,
                              hipStream_t stream) {
    const float* x      = (const float*)d_in[0];
    const float* freqs  = (const float*)d_in[2];
    const float* w_qkv  = (const float*)d_in[3];
    const float* b_qkv  = (const float*)d_in[4];
    const float* w_proj = (const float*)d_in[5];
    const float* b_proj = (const float*)d_in[6];
    float* out = (float*)d_out;

    unsigned short* ws = (unsigned short*)d_ws;
    const size_t HSZ = (size_t)2 * NH * S_LEN * HD;   // 4,194,304 shorts
    unsigned short* qb  = ws;
    unsigned short* kb  = ws + HSZ;
    unsigned short* vb  = ws + 2 * HSZ;
    unsigned short* ao  = ws + 3 * HSZ;
    unsigned short* xb  = ws + 4 * HSZ;                       // 4096x1024 bf16
    unsigned short* wqb = xb + (size_t)4096 * 1024;           // 3072x1024 bf16
    unsigned short* wpb = wqb + (size_t)3072 * 1024;          // 1024x1024 bf16
    float2* cs = (float2*)(wpb + (size_t)1024 * 1024);        // 2048x32 (cos,sin)

    prep_kernel<<<2048, 256, 0, stream>>>(x, w_qkv, w_proj, freqs, xb, wqb, wpb, cs);
    qkv_gemm_kernel<<<768, 256, 0, stream>>>(xb, wqb, b_qkv, cs, qb, kb, vb);
    attn_kernel<<<1024, 256, 0, stream>>>(qb, kb, vb, ao);
    proj_kernel<<<512, 256, 0, stream>>>(ao, wpb, b_proj, out);
}